// Round 7
// baseline (288.311 us; speedup 1.0000x reference)
//
#include <hip/hip_runtime.h>
#include <math.h>

#define BHn 16
#define SLEN 4096
#define Dd 64
#define Cc 64
#define NCC 64
#define EPSF 1e-6f
#define PD 65

// ---------------------------------------------------------------------------
// kA: two chunks per block (nA=px, nB=px+32), grid 32x16 = 512 blocks = 2/CU,
// fully co-resident in one round. Phases (2 barriers total):
//   1. k -> KTa/KTb = kn^T (shuffle norms, transposed writes); beta -> gla/glb
//   2. S for both chunks: 272 lower 4x4 tile-jobs over 256 threads (balanced)
//   3. (no barrier after sol load) wave0/2: W columns from KT*g;
//      wave1/3: U columns straight from global v (coalesced strided) * g;
//      all 4 waves run the register forward substitution concurrently;
//      direct register stores (sol never crosses a barrier -> no spill).
// ---------------------------------------------------------------------------
__global__ __launch_bounds__(256, 2) void kA(
    const float* __restrict__ kg, const float* __restrict__ vg,
    const float* __restrict__ betag, float* __restrict__ WTg, float* __restrict__ UTg,
    float* __restrict__ wlast, float* __restrict__ ulast)
{
    const int px = blockIdx.x, bh = blockIdx.y, tid = threadIdx.x;
    __shared__ float KTa[64 * PD];
    __shared__ float KTb[64 * PD];
    __shared__ float SMa[64 * PD];
    __shared__ float SMb[64 * PD];
    __shared__ float gla[64], glb[64];

    const int nA = px, nB = px + 32;
    const size_t baseA = ((size_t)bh * SLEN + (size_t)nA * Cc) * Dd;
    const size_t baseB = ((size_t)bh * SLEN + (size_t)nB * Cc) * Dd;

    if (tid < 64) {
        const float b = betag[(size_t)bh * SLEN + nA * Cc + tid];
        gla[tid] = fminf(fmaxf(b, EPSF), 1.0f - EPSF);
    } else if (tid < 128) {
        const float b = betag[(size_t)bh * SLEN + nB * Cc + (tid - 64)];
        glb[tid - 64] = fminf(fmaxf(b, EPSF), 1.0f - EPSF);
    }
    // phase 1: KT = kn^T for both chunks (coalesced row loads, 16-lane norms)
#pragma unroll
    for (int cc = 0; cc < 2; ++cc) {
        const float* src = kg + (cc ? baseB : baseA);
        float* KT = cc ? KTb : KTa;
#pragma unroll
        for (int p = 0; p < 4; p++) {
            const int flat = p * 1024 + tid * 4;
            const int row = flat >> 6, d0 = flat & 63;
            const float4 a = *(const float4*)(src + flat);
            float ss = a.x * a.x + a.y * a.y + a.z * a.z + a.w * a.w;
            ss += __shfl_xor(ss, 1); ss += __shfl_xor(ss, 2);
            ss += __shfl_xor(ss, 4); ss += __shfl_xor(ss, 8);
            const float inv = 1.0f / (sqrtf(ss) + EPSF);
            KT[(d0 + 0) * PD + row] = a.x * inv;
            KT[(d0 + 1) * PD + row] = a.y * inv;
            KT[(d0 + 2) * PD + row] = a.z * inv;
            KT[(d0 + 3) * PD + row] = a.w * inv;
        }
    }
    __syncthreads();

    // phase 2: S lower 4x4 tiles, 272 jobs (136 per chunk) over 256 threads
#pragma unroll
    for (int jj = 0; jj < 2; ++jj) {
        int chunk, tile;
        if (jj == 0) {
            chunk = (tid < 136) ? 0 : 1;
            tile  = (tid < 136) ? tid : tid - 136;
        } else {
            if (tid >= 16) break;
            chunk = 1; tile = 120 + tid;
        }
        const float* KT = chunk ? KTb : KTa;
        float* SM = chunk ? SMb : SMa;
        const float* gl = chunk ? glb : gla;
        int ti = (int)((sqrtf(8.0f * (float)tile + 1.0f) - 1.0f) * 0.5f);
        while (ti * (ti + 1) / 2 > tile) --ti;
        while ((ti + 1) * (ti + 2) / 2 <= tile) ++ti;
        const int tj = tile - ti * (ti + 1) / 2;
        const int i0 = ti * 4, j0 = tj * 4;
        float sa[4][4];
#pragma unroll
        for (int r = 0; r < 4; r++)
#pragma unroll
            for (int c2 = 0; c2 < 4; c2++) sa[r][c2] = 0.f;
        for (int d = 0; d < 64; d++) {
            const float4 a = *(const float4*)&KT[d * PD + i0];
            const float4 b = *(const float4*)&KT[d * PD + j0];
            const float av[4] = {a.x, a.y, a.z, a.w};
            const float bv[4] = {b.x, b.y, b.z, b.w};
#pragma unroll
            for (int r = 0; r < 4; r++)
#pragma unroll
                for (int c2 = 0; c2 < 4; c2++) sa[r][c2] += av[r] * bv[c2];
        }
#pragma unroll
        for (int r = 0; r < 4; r++) {
            const float gg = gl[i0 + r];
            *(float4*)&SM[(i0 + r) * PD + j0] =
                make_float4(sa[r][0] * gg, sa[r][1] * gg, sa[r][2] * gg, sa[r][3] * gg);
        }
    }
    __syncthreads();

    // phase 3: load solve columns (no further barriers; sol stays in regs)
    const int wv = tid >> 6, c = tid & 63;
    float sol[64];
    if ((wv & 1) == 0) {
        // W columns: KT row c * g  (b128 reads, conflict-free pad-65)
        const float* KT = (wv == 0) ? KTa : KTb;
        const float* gl = (wv == 0) ? gla : glb;
#pragma unroll
        for (int j4 = 0; j4 < 16; j4++) {
            const float4 t4 = *(const float4*)&KT[c * PD + j4 * 4];
            sol[j4 * 4 + 0] = t4.x * gl[j4 * 4 + 0];
            sol[j4 * 4 + 1] = t4.y * gl[j4 * 4 + 1];
            sol[j4 * 4 + 2] = t4.z * gl[j4 * 4 + 2];
            sol[j4 * 4 + 3] = t4.w * gl[j4 * 4 + 3];
        }
    } else {
        // U columns: straight from global v, per-instruction coalesced (lane=dim)
        const float* vsrc = vg + ((wv == 1) ? baseA : baseB) + c;
        const float* gl = (wv == 1) ? gla : glb;
#pragma unroll
        for (int t = 0; t < 64; t++)
            sol[t] = vsrc[(size_t)t * 64] * gl[t];
    }

    // phase 4: register forward substitution; SM reads wave-uniform broadcasts
    {
        const float* SM = (wv < 2) ? SMa : SMb;
#pragma unroll
        for (int b = 0; b < 8; b++) {
            const int i0 = b * 8;
            float acc[8];
#pragma unroll
            for (int r = 0; r < 8; r++) acc[r] = sol[i0 + r];
#pragma unroll
            for (int j4 = 0; j4 < 2 * b; j4++) {
                const int j = j4 * 4;
                const float s0 = sol[j + 0], s1 = sol[j + 1];
                const float s2 = sol[j + 2], s3 = sol[j + 3];
#pragma unroll
                for (int r = 0; r < 8; r++) {
                    const float4 m4 = *(const float4*)&SM[(i0 + r) * PD + j];
                    acc[r] -= m4.x * s0 + m4.y * s1 + m4.z * s2 + m4.w * s3;
                }
            }
#pragma unroll
            for (int il = 1; il < 8; il++)
#pragma unroll
                for (int jl = 0; jl < il; jl++)
                    acc[il] -= SM[(i0 + il) * PD + i0 + jl] * acc[jl];
#pragma unroll
            for (int r = 0; r < 8; r++) sol[i0 + r] = acc[r];
        }
    }

    // phase 5: direct register stores (row c of W^T / U^T, [dim][token])
    {
        const int n = (wv < 2) ? nA : nB;
        float* dst = ((wv & 1) ? UTg : WTg) +
                     (size_t)(bh * NCC + n) * Cc * Dd + (size_t)c * 64;
#pragma unroll
        for (int j4 = 0; j4 < 16; j4++)
            *(float4*)(dst + j4 * 4) = make_float4(sol[j4 * 4 + 0], sol[j4 * 4 + 1],
                                                   sol[j4 * 4 + 2], sol[j4 * 4 + 3]);
        float* lst = (wv & 1) ? ulast : wlast;
        lst[(size_t)(bh * NCC + n) * 64 + c] = sol[63];
    }
}

// ---------------------------------------------------------------------------
// kB: chunk-level delta rule (16 blocks). Register solve.  (round-5 verbatim)
// ---------------------------------------------------------------------------
__global__ __launch_bounds__(256) void kB(
    const float* __restrict__ wlast, const float* __restrict__ ulast,
    float* __restrict__ Uvg)
{
    const int bh = blockIdx.x, tid = threadIdx.x;
    __shared__ float WL[64 * PD];
    __shared__ float UL[64 * PD];
    __shared__ float SM[64 * PD];
    const size_t gbase = (size_t)bh * NCC * 64;

#pragma unroll
    for (int p = 0; p < 4; p++) {
        const int flat = p * 1024 + tid * 4;
        const int m = flat >> 6, d = flat & 63;
        *(float4*)&WL[m * PD + d] = *(const float4*)(wlast + gbase + flat);
        *(float4*)&UL[m * PD + d] = *(const float4*)(ulast + gbase + flat);
    }
    __syncthreads();

    if (tid < 136) {
        int ti = (int)((sqrtf(8.0f * (float)tid + 1.0f) - 1.0f) * 0.5f);
        while (ti * (ti + 1) / 2 > tid) --ti;
        while ((ti + 1) * (ti + 2) / 2 <= tid) ++ti;
        const int tj = tid - ti * (ti + 1) / 2;
        const int i0 = ti * 4, j0 = tj * 4;
        float sa[4][4];
#pragma unroll
        for (int r = 0; r < 4; r++)
#pragma unroll
            for (int c2 = 0; c2 < 4; c2++) sa[r][c2] = 0.f;
        for (int d4 = 0; d4 < 16; d4++) {
            const int d = d4 * 4;
            float4 ar[4], bc[4];
#pragma unroll
            for (int r = 0; r < 4; r++) ar[r] = *(const float4*)&WL[(i0 + r) * PD + d];
#pragma unroll
            for (int c2 = 0; c2 < 4; c2++) bc[c2] = *(const float4*)&WL[(j0 + c2) * PD + d];
#pragma unroll
            for (int r = 0; r < 4; r++)
#pragma unroll
                for (int c2 = 0; c2 < 4; c2++)
                    sa[r][c2] += ar[r].x * bc[c2].x + ar[r].y * bc[c2].y +
                                 ar[r].z * bc[c2].z + ar[r].w * bc[c2].w;
        }
#pragma unroll
        for (int r = 0; r < 4; r++)
            *(float4*)&SM[(i0 + r) * PD + j0] =
                make_float4(sa[r][0], sa[r][1], sa[r][2], sa[r][3]);
    }
    __syncthreads();

    if (tid < 64) {
        const int e = tid;
        float sol[64];
#pragma unroll
        for (int m = 0; m < 64; m++) sol[m] = UL[m * PD + e];
#pragma unroll
        for (int b = 0; b < 8; b++) {
            const int i0 = b * 8;
            float acc[8];
#pragma unroll
            for (int r = 0; r < 8; r++) acc[r] = sol[i0 + r];
#pragma unroll
            for (int j4 = 0; j4 < 2 * b; j4++) {
                const int j = j4 * 4;
                const float s0 = sol[j + 0], s1 = sol[j + 1];
                const float s2 = sol[j + 2], s3 = sol[j + 3];
#pragma unroll
                for (int r = 0; r < 8; r++) {
                    const float4 m4 = *(const float4*)&SM[(i0 + r) * PD + j];
                    acc[r] -= m4.x * s0 + m4.y * s1 + m4.z * s2 + m4.w * s3;
                }
            }
#pragma unroll
            for (int il = 1; il < 8; il++)
#pragma unroll
                for (int jl = 0; jl < il; jl++)
                    acc[il] -= SM[(i0 + il) * PD + i0 + jl] * acc[jl];
#pragma unroll
            for (int r = 0; r < 8; r++) sol[i0 + r] = acc[r];
        }
#pragma unroll
        for (int m = 0; m < 64; m++) Uvg[gbase + (size_t)m * 64 + e] = sol[m];
    }
}

// ---------------------------------------------------------------------------
// kC: output, balanced chunk pairs (63-px, px).  (round-5 verbatim)
// ---------------------------------------------------------------------------
__global__ __launch_bounds__(256, 3) void kC(
    const float* __restrict__ qg, const float* __restrict__ WTg,
    const float* __restrict__ UTg, const float* __restrict__ wlast,
    const float* __restrict__ Uvg, float* __restrict__ outg)
{
    const int px = blockIdx.x, bh = blockIdx.y, tid = threadIdx.x;
    __shared__ float X1[64 * 64];
    __shared__ float X2[64 * PD];
    __shared__ float HB[64 * 64];
    const size_t lbase = (size_t)bh * NCC * 64;
    const int t0 = (tid >> 4) * 4, e0 = (tid & 15) * 4;

    for (int pass = 0; pass < 2; ++pass) {
        const int n = pass ? px : 63 - px;
        const size_t qbase = ((size_t)bh * SLEN + (size_t)n * Cc) * Dd;
        const size_t wbase = (size_t)(bh * NCC + n) * Cc * Dd;
        if (pass) __syncthreads();

        float4 qa[4], wt[4];
        float qinv[4];
#pragma unroll
        for (int p = 0; p < 4; p++) {
            const int flat = p * 1024 + tid * 4;
            const int m = flat >> 6, d = flat & 63;
            *(float4*)&X1[m * 64 + d] = *(const float4*)(wlast + lbase + flat);
            *(float4*)&X2[m * PD + d] = *(const float4*)(Uvg + lbase + flat);
            qa[p] = *(const float4*)(qg + qbase + flat);
            float ss = qa[p].x * qa[p].x + qa[p].y * qa[p].y +
                       qa[p].z * qa[p].z + qa[p].w * qa[p].w;
            ss += __shfl_xor(ss, 1); ss += __shfl_xor(ss, 2);
            ss += __shfl_xor(ss, 4); ss += __shfl_xor(ss, 8);
            qinv[p] = 1.0f / (sqrtf(ss) + EPSF);
            wt[p] = *(const float4*)(WTg + wbase + flat);
        }
        __syncthreads();

        float ha[4][4];
#pragma unroll
        for (int r = 0; r < 4; r++)
#pragma unroll
            for (int c2 = 0; c2 < 4; c2++) ha[r][c2] = 0.f;
        for (int m = 0; m < n; m++) {
            const float4 a = *(const float4*)&X1[m * 64 + t0];
            const float4 b = *(const float4*)&X2[m * PD + e0];
            const float av[4] = {a.x, a.y, a.z, a.w};
            const float bv[4] = {b.x, b.y, b.z, b.w};
#pragma unroll
            for (int r = 0; r < 4; r++)
#pragma unroll
                for (int c2 = 0; c2 < 4; c2++) ha[r][c2] += av[r] * bv[c2];
        }
#pragma unroll
        for (int r = 0; r < 4; r++)
            *(float4*)&HB[(t0 + r) * 64 + e0] =
                make_float4(ha[r][0], ha[r][1], ha[r][2], ha[r][3]);
        __syncthreads();

#pragma unroll
        for (int p = 0; p < 4; p++) {
            const int flat = p * 1024 + tid * 4;
            const int d = flat >> 6, t = flat & 63;
            *(float4*)&X1[d * 64 + t] = wt[p];
            const int row = d, d0 = t;
            X2[(d0 + 0) * PD + row] = qa[p].x * qinv[p];
            X2[(d0 + 1) * PD + row] = qa[p].y * qinv[p];
            X2[(d0 + 2) * PD + row] = qa[p].z * qinv[p];
            X2[(d0 + 3) * PD + row] = qa[p].w * qinv[p];
        }
        __syncthreads();

        float kth[4][4], oin[4][4];
#pragma unroll
        for (int r = 0; r < 4; r++)
#pragma unroll
            for (int c2 = 0; c2 < 4; c2++) { kth[r][c2] = 0.f; oin[r][c2] = 0.f; }
#pragma unroll 4
        for (int d = 0; d < 64; d++) {
            const float4 wv = *(const float4*)&X1[d * 64 + t0];
            const float4 qv = *(const float4*)&X2[d * PD + t0];
            const float4 hv = *(const float4*)&HB[d * 64 + e0];
            const float wa[4] = {wv.x, wv.y, wv.z, wv.w};
            const float qa2[4] = {qv.x, qv.y, qv.z, qv.w};
            const float hv4[4] = {hv.x, hv.y, hv.z, hv.w};
#pragma unroll
            for (int r = 0; r < 4; r++)
#pragma unroll
                for (int c2 = 0; c2 < 4; c2++) {
                    kth[r][c2] += wa[r] * hv4[c2];
                    oin[r][c2] += qa2[r] * hv4[c2];
                }
        }

        float* oc = outg + qbase;
        float o4[4][4];
#pragma unroll
        for (int s = 0; s < 4; s++) {
            const float4 u4 = *(const float4*)(UTg + wbase + (size_t)(e0 + s) * 64 + t0);
            const float4 q4 = *(const float4*)&X2[(e0 + s) * PD + t0];
            o4[0][s] = q4.x * (u4.x - kth[0][s]) + oin[0][s];
            o4[1][s] = q4.y * (u4.y - kth[1][s]) + oin[1][s];
            o4[2][s] = q4.z * (u4.z - kth[2][s]) + oin[2][s];
            o4[3][s] = q4.w * (u4.w - kth[3][s]) + oin[3][s];
        }
#pragma unroll
        for (int r = 0; r < 4; r++)
            *(float4*)(oc + (size_t)(t0 + r) * 64 + e0) =
                make_float4(o4[r][0], o4[r][1], o4[r][2], o4[r][3]);
    }
}

extern "C" void kernel_launch(void* const* d_in, const int* in_sizes, int n_in,
                              void* d_out, int out_size, void* d_ws, size_t ws_size,
                              hipStream_t stream) {
    const float* q    = (const float*)d_in[0];
    const float* k    = (const float*)d_in[1];
    const float* v    = (const float*)d_in[2];
    const float* beta = (const float*)d_in[3];
    float* out = (float*)d_out;

    float* WTg   = (float*)d_ws;                              // [BH][NC][64][64]
    float* UTg   = WTg + (size_t)BHn * NCC * Cc * Dd;         // [BH][NC][64][64]
    float* wlast = UTg + (size_t)BHn * NCC * Cc * Dd;         // [BH][NC][64]
    float* ulast = wlast + (size_t)BHn * NCC * 64;            // [BH][NC][64]
    float* Uvg   = ulast + (size_t)BHn * NCC * 64;            // [BH][NC][64]

    kA<<<dim3(32, BHn), 256, 0, stream>>>(k, v, beta, WTg, UTg, wlast, ulast);
    kB<<<dim3(BHn), 256, 0, stream>>>(wlast, ulast, Uvg);
    kC<<<dim3(32, BHn), 256, 0, stream>>>(q, WTg, UTg, wlast, Uvg, out);
}

// Round 8
// 197.495 us; speedup vs baseline: 1.4598x; 1.4598x over previous
//
#include <hip/hip_runtime.h>
#include <math.h>

#define BHn 16
#define SLEN 4096
#define Dd 64
#define Cc 64
#define NCC 64
#define EPSF 1e-6f
#define PD 65

// ---------------------------------------------------------------------------
// kA: grid (32,16), 2 chunks per block (n = px, px+32), 3 blocks/CU resident.
//   KT[d][t] = kn^T, VT[d][t] = v^T (unscaled), SM = g_i*(kn_i.kn_j) lower.
//   S spread over 256 threads (272 2x4-tile jobs). Solve columns are loaded
//   from LDS *at solve time* (no barrier between load and use -> no scratch
//   spill; compiler may lazily re-read LDS). Direct register stores.
// ---------------------------------------------------------------------------
__global__ __launch_bounds__(256, 3) void kA(
    const float* __restrict__ kg, const float* __restrict__ vg,
    const float* __restrict__ betag, float* __restrict__ WTg, float* __restrict__ UTg,
    float* __restrict__ wlast, float* __restrict__ ulast)
{
    const int px = blockIdx.x, bh = blockIdx.y, tid = threadIdx.x;
    __shared__ float KT[64 * PD];   // kn^T
    __shared__ float VT[64 * PD];   // v^T (unscaled)
    __shared__ float SM[64 * PD];   // g-scaled S (lower)
    __shared__ float gl[64];

    for (int cc = 0; cc < 2; ++cc) {
        const int n = px + 32 * cc;
        const size_t base = ((size_t)bh * SLEN + (size_t)n * Cc) * Dd;
        if (cc) __syncthreads();   // previous iteration's LDS reads complete

        if (tid < 64) {
            const float b = betag[(size_t)bh * SLEN + n * Cc + tid];
            gl[tid] = fminf(fmaxf(b, EPSF), 1.0f - EPSF);
        }
        // phase 1: KT = kn^T, VT = v^T (coalesced row loads, 16-lane norms,
        // transposed scalar writes: 2 lanes/bank = free)
#pragma unroll
        for (int p = 0; p < 4; p++) {
            const int flat = p * 1024 + tid * 4;
            const int row = flat >> 6, d0 = flat & 63;
            const float4 a = *(const float4*)(kg + base + flat);
            float ss = a.x * a.x + a.y * a.y + a.z * a.z + a.w * a.w;
            ss += __shfl_xor(ss, 1); ss += __shfl_xor(ss, 2);
            ss += __shfl_xor(ss, 4); ss += __shfl_xor(ss, 8);
            const float inv = 1.0f / (sqrtf(ss) + EPSF);
            KT[(d0 + 0) * PD + row] = a.x * inv;
            KT[(d0 + 1) * PD + row] = a.y * inv;
            KT[(d0 + 2) * PD + row] = a.z * inv;
            KT[(d0 + 3) * PD + row] = a.w * inv;
            const float4 vv = *(const float4*)(vg + base + flat);
            VT[(d0 + 0) * PD + row] = vv.x;
            VT[(d0 + 1) * PD + row] = vv.y;
            VT[(d0 + 2) * PD + row] = vv.z;
            VT[(d0 + 3) * PD + row] = vv.w;
        }
        __syncthreads();

        // phase 2: S lower tiles as 272 2x4 jobs over 256 threads
#pragma unroll
        for (int jj = 0; jj < 2; ++jj) {
            if (jj && tid >= 16) break;
            const int job = jj ? 256 + tid : tid;
            const int tile = job >> 1, half = job & 1;
            int ti = (int)((sqrtf(8.0f * (float)tile + 1.0f) - 1.0f) * 0.5f);
            while (ti * (ti + 1) / 2 > tile) --ti;
            while ((ti + 1) * (ti + 2) / 2 <= tile) ++ti;
            const int tj = tile - ti * (ti + 1) / 2;
            const int i0 = ti * 4 + half * 2, j0 = tj * 4;
            float sa[2][4];
#pragma unroll
            for (int r = 0; r < 2; r++)
#pragma unroll
                for (int c2 = 0; c2 < 4; c2++) sa[r][c2] = 0.f;
            for (int d = 0; d < 64; d++) {
                const float2 a = *(const float2*)&KT[d * PD + i0];
                const float4 b = *(const float4*)&KT[d * PD + j0];
                sa[0][0] += a.x * b.x; sa[0][1] += a.x * b.y;
                sa[0][2] += a.x * b.z; sa[0][3] += a.x * b.w;
                sa[1][0] += a.y * b.x; sa[1][1] += a.y * b.y;
                sa[1][2] += a.y * b.z; sa[1][3] += a.y * b.w;
            }
#pragma unroll
            for (int r = 0; r < 2; r++) {
                const float gg = gl[i0 + r];
                *(float4*)&SM[(i0 + r) * PD + j0] =
                    make_float4(sa[r][0] * gg, sa[r][1] * gg, sa[r][2] * gg, sa[r][3] * gg);
            }
        }
        __syncthreads();

        // phase 3: solve (waves 0-1). Columns loaded from LDS HERE (no barrier
        // between load and use); SM reads are wave-uniform broadcasts.
        if (tid < 128) {
            const int c = tid & 63;
            const float* colsrc = (tid < 64) ? &KT[c * PD] : &VT[c * PD];
            float sol[64];
#pragma unroll
            for (int j4 = 0; j4 < 16; j4++) {
                const float4 t4 = *(const float4*)&colsrc[j4 * 4];
                sol[j4 * 4 + 0] = t4.x * gl[j4 * 4 + 0];
                sol[j4 * 4 + 1] = t4.y * gl[j4 * 4 + 1];
                sol[j4 * 4 + 2] = t4.z * gl[j4 * 4 + 2];
                sol[j4 * 4 + 3] = t4.w * gl[j4 * 4 + 3];
            }
#pragma unroll
            for (int b = 0; b < 8; b++) {
                const int i0 = b * 8;
                float acc[8];
#pragma unroll
                for (int r = 0; r < 8; r++) acc[r] = sol[i0 + r];
#pragma unroll
                for (int j4 = 0; j4 < 2 * b; j4++) {
                    const int j = j4 * 4;
                    const float s0 = sol[j + 0], s1 = sol[j + 1];
                    const float s2 = sol[j + 2], s3 = sol[j + 3];
#pragma unroll
                    for (int r = 0; r < 8; r++) {
                        const float4 m4 = *(const float4*)&SM[(i0 + r) * PD + j];
                        acc[r] -= m4.x * s0 + m4.y * s1 + m4.z * s2 + m4.w * s3;
                    }
                }
#pragma unroll
                for (int il = 1; il < 8; il++)
#pragma unroll
                    for (int jl = 0; jl < il; jl++)
                        acc[il] -= SM[(i0 + il) * PD + i0 + jl] * acc[jl];
#pragma unroll
                for (int r = 0; r < 8; r++) sol[i0 + r] = acc[r];
            }
            // direct register stores: row c of W^T / U^T ([dim][token])
            float* dst = (tid < 64 ? WTg : UTg) +
                         (size_t)(bh * NCC + n) * Cc * Dd + (size_t)c * 64;
#pragma unroll
            for (int j4 = 0; j4 < 16; j4++)
                *(float4*)(dst + j4 * 4) = make_float4(sol[j4*4+0], sol[j4*4+1],
                                                       sol[j4*4+2], sol[j4*4+3]);
            float* lst = (tid < 64 ? wlast : ulast);
            lst[(size_t)(bh * NCC + n) * 64 + c] = sol[63];
        }
    }
}

// ---------------------------------------------------------------------------
// kB: chunk-level delta rule (16 blocks). Register solve.  (round-5 verbatim)
// ---------------------------------------------------------------------------
__global__ __launch_bounds__(256) void kB(
    const float* __restrict__ wlast, const float* __restrict__ ulast,
    float* __restrict__ Uvg)
{
    const int bh = blockIdx.x, tid = threadIdx.x;
    __shared__ float WL[64 * PD];
    __shared__ float UL[64 * PD];
    __shared__ float SM[64 * PD];
    const size_t gbase = (size_t)bh * NCC * 64;

#pragma unroll
    for (int p = 0; p < 4; p++) {
        const int flat = p * 1024 + tid * 4;
        const int m = flat >> 6, d = flat & 63;
        *(float4*)&WL[m * PD + d] = *(const float4*)(wlast + gbase + flat);
        *(float4*)&UL[m * PD + d] = *(const float4*)(ulast + gbase + flat);
    }
    __syncthreads();

    if (tid < 136) {
        int ti = (int)((sqrtf(8.0f * (float)tid + 1.0f) - 1.0f) * 0.5f);
        while (ti * (ti + 1) / 2 > tid) --ti;
        while ((ti + 1) * (ti + 2) / 2 <= tid) ++ti;
        const int tj = tid - ti * (ti + 1) / 2;
        const int i0 = ti * 4, j0 = tj * 4;
        float sa[4][4];
#pragma unroll
        for (int r = 0; r < 4; r++)
#pragma unroll
            for (int c2 = 0; c2 < 4; c2++) sa[r][c2] = 0.f;
        for (int d4 = 0; d4 < 16; d4++) {
            const int d = d4 * 4;
            float4 ar[4], bc[4];
#pragma unroll
            for (int r = 0; r < 4; r++) ar[r] = *(const float4*)&WL[(i0 + r) * PD + d];
#pragma unroll
            for (int c2 = 0; c2 < 4; c2++) bc[c2] = *(const float4*)&WL[(j0 + c2) * PD + d];
#pragma unroll
            for (int r = 0; r < 4; r++)
#pragma unroll
                for (int c2 = 0; c2 < 4; c2++)
                    sa[r][c2] += ar[r].x * bc[c2].x + ar[r].y * bc[c2].y +
                                 ar[r].z * bc[c2].z + ar[r].w * bc[c2].w;
        }
#pragma unroll
        for (int r = 0; r < 4; r++)
            *(float4*)&SM[(i0 + r) * PD + j0] =
                make_float4(sa[r][0], sa[r][1], sa[r][2], sa[r][3]);
    }
    __syncthreads();

    if (tid < 64) {
        const int e = tid;
        float sol[64];
#pragma unroll
        for (int m = 0; m < 64; m++) sol[m] = UL[m * PD + e];
#pragma unroll
        for (int b = 0; b < 8; b++) {
            const int i0 = b * 8;
            float acc[8];
#pragma unroll
            for (int r = 0; r < 8; r++) acc[r] = sol[i0 + r];
#pragma unroll
            for (int j4 = 0; j4 < 2 * b; j4++) {
                const int j = j4 * 4;
                const float s0 = sol[j + 0], s1 = sol[j + 1];
                const float s2 = sol[j + 2], s3 = sol[j + 3];
#pragma unroll
                for (int r = 0; r < 8; r++) {
                    const float4 m4 = *(const float4*)&SM[(i0 + r) * PD + j];
                    acc[r] -= m4.x * s0 + m4.y * s1 + m4.z * s2 + m4.w * s3;
                }
            }
#pragma unroll
            for (int il = 1; il < 8; il++)
#pragma unroll
                for (int jl = 0; jl < il; jl++)
                    acc[il] -= SM[(i0 + il) * PD + i0 + jl] * acc[jl];
#pragma unroll
            for (int r = 0; r < 8; r++) sol[i0 + r] = acc[r];
        }
#pragma unroll
        for (int m = 0; m < 64; m++) Uvg[gbase + (size_t)m * 64 + e] = sol[m];
    }
}

// ---------------------------------------------------------------------------
// kC: output, balanced chunk pairs (63-px, px).  (round-5 verbatim)
// ---------------------------------------------------------------------------
__global__ __launch_bounds__(256, 3) void kC(
    const float* __restrict__ qg, const float* __restrict__ WTg,
    const float* __restrict__ UTg, const float* __restrict__ wlast,
    const float* __restrict__ Uvg, float* __restrict__ outg)
{
    const int px = blockIdx.x, bh = blockIdx.y, tid = threadIdx.x;
    __shared__ float X1[64 * 64];
    __shared__ float X2[64 * PD];
    __shared__ float HB[64 * 64];
    const size_t lbase = (size_t)bh * NCC * 64;
    const int t0 = (tid >> 4) * 4, e0 = (tid & 15) * 4;

    for (int pass = 0; pass < 2; ++pass) {
        const int n = pass ? px : 63 - px;
        const size_t qbase = ((size_t)bh * SLEN + (size_t)n * Cc) * Dd;
        const size_t wbase = (size_t)(bh * NCC + n) * Cc * Dd;
        if (pass) __syncthreads();

        float4 qa[4], wt[4];
        float qinv[4];
#pragma unroll
        for (int p = 0; p < 4; p++) {
            const int flat = p * 1024 + tid * 4;
            const int m = flat >> 6, d = flat & 63;
            *(float4*)&X1[m * 64 + d] = *(const float4*)(wlast + lbase + flat);
            *(float4*)&X2[m * PD + d] = *(const float4*)(Uvg + lbase + flat);
            qa[p] = *(const float4*)(qg + qbase + flat);
            float ss = qa[p].x * qa[p].x + qa[p].y * qa[p].y +
                       qa[p].z * qa[p].z + qa[p].w * qa[p].w;
            ss += __shfl_xor(ss, 1); ss += __shfl_xor(ss, 2);
            ss += __shfl_xor(ss, 4); ss += __shfl_xor(ss, 8);
            qinv[p] = 1.0f / (sqrtf(ss) + EPSF);
            wt[p] = *(const float4*)(WTg + wbase + flat);
        }
        __syncthreads();

        float ha[4][4];
#pragma unroll
        for (int r = 0; r < 4; r++)
#pragma unroll
            for (int c2 = 0; c2 < 4; c2++) ha[r][c2] = 0.f;
        for (int m = 0; m < n; m++) {
            const float4 a = *(const float4*)&X1[m * 64 + t0];
            const float4 b = *(const float4*)&X2[m * PD + e0];
            const float av[4] = {a.x, a.y, a.z, a.w};
            const float bv[4] = {b.x, b.y, b.z, b.w};
#pragma unroll
            for (int r = 0; r < 4; r++)
#pragma unroll
                for (int c2 = 0; c2 < 4; c2++) ha[r][c2] += av[r] * bv[c2];
        }
#pragma unroll
        for (int r = 0; r < 4; r++)
            *(float4*)&HB[(t0 + r) * 64 + e0] =
                make_float4(ha[r][0], ha[r][1], ha[r][2], ha[r][3]);
        __syncthreads();

#pragma unroll
        for (int p = 0; p < 4; p++) {
            const int flat = p * 1024 + tid * 4;
            const int d = flat >> 6, t = flat & 63;
            *(float4*)&X1[d * 64 + t] = wt[p];
            const int row = d, d0 = t;
            X2[(d0 + 0) * PD + row] = qa[p].x * qinv[p];
            X2[(d0 + 1) * PD + row] = qa[p].y * qinv[p];
            X2[(d0 + 2) * PD + row] = qa[p].z * qinv[p];
            X2[(d0 + 3) * PD + row] = qa[p].w * qinv[p];
        }
        __syncthreads();

        float kth[4][4], oin[4][4];
#pragma unroll
        for (int r = 0; r < 4; r++)
#pragma unroll
            for (int c2 = 0; c2 < 4; c2++) { kth[r][c2] = 0.f; oin[r][c2] = 0.f; }
#pragma unroll 4
        for (int d = 0; d < 64; d++) {
            const float4 wv = *(const float4*)&X1[d * 64 + t0];
            const float4 qv = *(const float4*)&X2[d * PD + t0];
            const float4 hv = *(const float4*)&HB[d * 64 + e0];
            const float wa[4] = {wv.x, wv.y, wv.z, wv.w};
            const float qa2[4] = {qv.x, qv.y, qv.z, qv.w};
            const float hv4[4] = {hv.x, hv.y, hv.z, hv.w};
#pragma unroll
            for (int r = 0; r < 4; r++)
#pragma unroll
                for (int c2 = 0; c2 < 4; c2++) {
                    kth[r][c2] += wa[r] * hv4[c2];
                    oin[r][c2] += qa2[r] * hv4[c2];
                }
        }

        float* oc = outg + qbase;
        float o4[4][4];
#pragma unroll
        for (int s = 0; s < 4; s++) {
            const float4 u4 = *(const float4*)(UTg + wbase + (size_t)(e0 + s) * 64 + t0);
            const float4 q4 = *(const float4*)&X2[(e0 + s) * PD + t0];
            o4[0][s] = q4.x * (u4.x - kth[0][s]) + oin[0][s];
            o4[1][s] = q4.y * (u4.y - kth[1][s]) + oin[1][s];
            o4[2][s] = q4.z * (u4.z - kth[2][s]) + oin[2][s];
            o4[3][s] = q4.w * (u4.w - kth[3][s]) + oin[3][s];
        }
#pragma unroll
        for (int r = 0; r < 4; r++)
            *(float4*)(oc + (size_t)(t0 + r) * 64 + e0) =
                make_float4(o4[r][0], o4[r][1], o4[r][2], o4[r][3]);
    }
}

extern "C" void kernel_launch(void* const* d_in, const int* in_sizes, int n_in,
                              void* d_out, int out_size, void* d_ws, size_t ws_size,
                              hipStream_t stream) {
    const float* q    = (const float*)d_in[0];
    const float* k    = (const float*)d_in[1];
    const float* v    = (const float*)d_in[2];
    const float* beta = (const float*)d_in[3];
    float* out = (float*)d_out;

    float* WTg   = (float*)d_ws;                              // [BH][NC][64][64]
    float* UTg   = WTg + (size_t)BHn * NCC * Cc * Dd;         // [BH][NC][64][64]
    float* wlast = UTg + (size_t)BHn * NCC * Cc * Dd;         // [BH][NC][64]
    float* ulast = wlast + (size_t)BHn * NCC * 64;            // [BH][NC][64]
    float* Uvg   = ulast + (size_t)BHn * NCC * 64;            // [BH][NC][64]

    kA<<<dim3(32, BHn), 256, 0, stream>>>(k, v, beta, WTg, UTg, wlast, ulast);
    kB<<<dim3(BHn), 256, 0, stream>>>(wlast, ulast, Uvg);
    kC<<<dim3(32, BHn), 256, 0, stream>>>(q, WTg, UTg, wlast, Uvg, out);
}

// Round 9
// 170.190 us; speedup vs baseline: 1.6941x; 1.1604x over previous
//
#include <hip/hip_runtime.h>
#include <math.h>

#define BHn 16
#define SLEN 4096
#define Dd 64
#define Cc 64
#define NCC 64
#define EPSF 1e-6f
#define PD 65

// ---------------------------------------------------------------------------
// kA: grid (64,16), one chunk per block. LDS-issue-optimized:
//   KT[d][t] = kn^T; SM = g_i*(kn_i.kn_j) lower (threads 64..199).
//   Wave0 solves W AND U columns together in one register sweep -> every SM
//   broadcast read feeds both chains (672 instead of 1344 LDS instr/chunk).
//   U RHS comes straight from global v at solve time (coalesced 256B/instr);
//   no VT staging, no overwrite phase, 2 barriers total, 33.5 KB LDS.
//   sol arrays never cross a barrier (spill rule).
// ---------------------------------------------------------------------------
__global__ __launch_bounds__(256, 2) void kA(
    const float* __restrict__ kg, const float* __restrict__ vg,
    const float* __restrict__ betag, float* __restrict__ WTg, float* __restrict__ UTg,
    float* __restrict__ wlast, float* __restrict__ ulast)
{
    const int n = blockIdx.x, bh = blockIdx.y, tid = threadIdx.x;
    __shared__ float KT[64 * PD];   // kn^T
    __shared__ float SM[64 * PD];   // g-scaled S (lower)
    __shared__ float gl[64];

    const size_t base = ((size_t)bh * SLEN + (size_t)n * Cc) * Dd;

    if (tid < 64) {
        const float b = betag[(size_t)bh * SLEN + n * Cc + tid];
        gl[tid] = fminf(fmaxf(b, EPSF), 1.0f - EPSF);
    }
    // phase 1: KT = kn^T (coalesced float4 row loads, 16-lane shuffle norms,
    // transposed scalar writes: bank=(d+t)%32 -> 2 lanes/bank = free)
#pragma unroll
    for (int p = 0; p < 4; p++) {
        const int flat = p * 1024 + tid * 4;
        const int row = flat >> 6, d0 = flat & 63;
        const float4 a = *(const float4*)(kg + base + flat);
        float ss = a.x * a.x + a.y * a.y + a.z * a.z + a.w * a.w;
        ss += __shfl_xor(ss, 1); ss += __shfl_xor(ss, 2);
        ss += __shfl_xor(ss, 4); ss += __shfl_xor(ss, 8);
        const float inv = 1.0f / (sqrtf(ss) + EPSF);
        KT[(d0 + 0) * PD + row] = a.x * inv;
        KT[(d0 + 1) * PD + row] = a.y * inv;
        KT[(d0 + 2) * PD + row] = a.z * inv;
        KT[(d0 + 3) * PD + row] = a.w * inv;
    }
    __syncthreads();

    // phase 2: S lower 4x4 tiles on threads 64..199 (wave0 stays free)
    if (tid >= 64 && tid < 200) {
        const int t = tid - 64;
        int ti = (int)((sqrtf(8.0f * (float)t + 1.0f) - 1.0f) * 0.5f);
        while (ti * (ti + 1) / 2 > t) --ti;
        while ((ti + 1) * (ti + 2) / 2 <= t) ++ti;
        const int tj = t - ti * (ti + 1) / 2;
        const int i0 = ti * 4, j0 = tj * 4;
        float sa[4][4];
#pragma unroll
        for (int r = 0; r < 4; r++)
#pragma unroll
            for (int c2 = 0; c2 < 4; c2++) sa[r][c2] = 0.f;
        for (int d = 0; d < 64; d++) {
            const float4 a = *(const float4*)&KT[d * PD + i0];
            const float4 b = *(const float4*)&KT[d * PD + j0];
            const float av[4] = {a.x, a.y, a.z, a.w};
            const float bv[4] = {b.x, b.y, b.z, b.w};
#pragma unroll
            for (int r = 0; r < 4; r++)
#pragma unroll
                for (int c2 = 0; c2 < 4; c2++) sa[r][c2] += av[r] * bv[c2];
        }
#pragma unroll
        for (int r = 0; r < 4; r++) {
            const float gg = gl[i0 + r];
            *(float4*)&SM[(i0 + r) * PD + j0] =
                make_float4(sa[r][0] * gg, sa[r][1] * gg, sa[r][2] * gg, sa[r][3] * gg);
        }
    }
    __syncthreads();

    // phase 3: wave0 solves W and U columns together (no further barriers).
    if (tid < 64) {
        const int c = tid;
        float solw[64], solu[64];
        // W RHS: KT row c (b128, 2-way banks) * g ; U RHS: global v (coalesced
        // 256B wave transactions) * g (gl reads are broadcasts)
#pragma unroll
        for (int j4 = 0; j4 < 16; j4++) {
            const float4 t4 = *(const float4*)&KT[c * PD + j4 * 4];
            solw[j4 * 4 + 0] = t4.x * gl[j4 * 4 + 0];
            solw[j4 * 4 + 1] = t4.y * gl[j4 * 4 + 1];
            solw[j4 * 4 + 2] = t4.z * gl[j4 * 4 + 2];
            solw[j4 * 4 + 3] = t4.w * gl[j4 * 4 + 3];
        }
        const float* vsrc = vg + base + c;
#pragma unroll
        for (int t = 0; t < 64; t++)
            solu[t] = vsrc[(size_t)t * 64] * gl[t];

        // blocked forward substitution; SM broadcasts feed BOTH chains
#pragma unroll
        for (int b = 0; b < 8; b++) {
            const int i0 = b * 8;
            float aw[8], au[8];
#pragma unroll
            for (int r = 0; r < 8; r++) { aw[r] = solw[i0 + r]; au[r] = solu[i0 + r]; }
#pragma unroll
            for (int j4 = 0; j4 < 2 * b; j4++) {
                const int j = j4 * 4;
                const float w0 = solw[j + 0], w1 = solw[j + 1];
                const float w2 = solw[j + 2], w3 = solw[j + 3];
                const float u0 = solu[j + 0], u1 = solu[j + 1];
                const float u2 = solu[j + 2], u3 = solu[j + 3];
#pragma unroll
                for (int r = 0; r < 8; r++) {
                    const float4 m4 = *(const float4*)&SM[(i0 + r) * PD + j];
                    aw[r] -= m4.x * w0 + m4.y * w1 + m4.z * w2 + m4.w * w3;
                    au[r] -= m4.x * u0 + m4.y * u1 + m4.z * u2 + m4.w * u3;
                }
            }
#pragma unroll
            for (int il = 1; il < 8; il++)
#pragma unroll
                for (int jl = 0; jl < il; jl++) {
                    const float s = SM[(i0 + il) * PD + i0 + jl];
                    aw[il] -= s * aw[jl];
                    au[il] -= s * au[jl];
                }
#pragma unroll
            for (int r = 0; r < 8; r++) { solw[i0 + r] = aw[r]; solu[i0 + r] = au[r]; }
        }

        // direct register stores: row c of W^T and U^T ([dim][token])
        float* wdst = WTg + (size_t)(bh * NCC + n) * Cc * Dd + (size_t)c * 64;
        float* udst = UTg + (size_t)(bh * NCC + n) * Cc * Dd + (size_t)c * 64;
#pragma unroll
        for (int j4 = 0; j4 < 16; j4++) {
            *(float4*)(wdst + j4 * 4) = make_float4(solw[j4*4+0], solw[j4*4+1],
                                                    solw[j4*4+2], solw[j4*4+3]);
            *(float4*)(udst + j4 * 4) = make_float4(solu[j4*4+0], solu[j4*4+1],
                                                    solu[j4*4+2], solu[j4*4+3]);
        }
        wlast[(size_t)(bh * NCC + n) * 64 + c] = solw[63];
        ulast[(size_t)(bh * NCC + n) * 64 + c] = solu[63];
    }
}

// ---------------------------------------------------------------------------
// kB: chunk-level delta rule (16 blocks). Register solve.  (round-5 verbatim)
// ---------------------------------------------------------------------------
__global__ __launch_bounds__(256) void kB(
    const float* __restrict__ wlast, const float* __restrict__ ulast,
    float* __restrict__ Uvg)
{
    const int bh = blockIdx.x, tid = threadIdx.x;
    __shared__ float WL[64 * PD];
    __shared__ float UL[64 * PD];
    __shared__ float SM[64 * PD];
    const size_t gbase = (size_t)bh * NCC * 64;

#pragma unroll
    for (int p = 0; p < 4; p++) {
        const int flat = p * 1024 + tid * 4;
        const int m = flat >> 6, d = flat & 63;
        *(float4*)&WL[m * PD + d] = *(const float4*)(wlast + gbase + flat);
        *(float4*)&UL[m * PD + d] = *(const float4*)(ulast + gbase + flat);
    }
    __syncthreads();

    if (tid < 136) {
        int ti = (int)((sqrtf(8.0f * (float)tid + 1.0f) - 1.0f) * 0.5f);
        while (ti * (ti + 1) / 2 > tid) --ti;
        while ((ti + 1) * (ti + 2) / 2 <= tid) ++ti;
        const int tj = tid - ti * (ti + 1) / 2;
        const int i0 = ti * 4, j0 = tj * 4;
        float sa[4][4];
#pragma unroll
        for (int r = 0; r < 4; r++)
#pragma unroll
            for (int c2 = 0; c2 < 4; c2++) sa[r][c2] = 0.f;
        for (int d4 = 0; d4 < 16; d4++) {
            const int d = d4 * 4;
            float4 ar[4], bc[4];
#pragma unroll
            for (int r = 0; r < 4; r++) ar[r] = *(const float4*)&WL[(i0 + r) * PD + d];
#pragma unroll
            for (int c2 = 0; c2 < 4; c2++) bc[c2] = *(const float4*)&WL[(j0 + c2) * PD + d];
#pragma unroll
            for (int r = 0; r < 4; r++)
#pragma unroll
                for (int c2 = 0; c2 < 4; c2++)
                    sa[r][c2] += ar[r].x * bc[c2].x + ar[r].y * bc[c2].y +
                                 ar[r].z * bc[c2].z + ar[r].w * bc[c2].w;
        }
#pragma unroll
        for (int r = 0; r < 4; r++)
            *(float4*)&SM[(i0 + r) * PD + j0] =
                make_float4(sa[r][0], sa[r][1], sa[r][2], sa[r][3]);
    }
    __syncthreads();

    if (tid < 64) {
        const int e = tid;
        float sol[64];
#pragma unroll
        for (int m = 0; m < 64; m++) sol[m] = UL[m * PD + e];
#pragma unroll
        for (int b = 0; b < 8; b++) {
            const int i0 = b * 8;
            float acc[8];
#pragma unroll
            for (int r = 0; r < 8; r++) acc[r] = sol[i0 + r];
#pragma unroll
            for (int j4 = 0; j4 < 2 * b; j4++) {
                const int j = j4 * 4;
                const float s0 = sol[j + 0], s1 = sol[j + 1];
                const float s2 = sol[j + 2], s3 = sol[j + 3];
#pragma unroll
                for (int r = 0; r < 8; r++) {
                    const float4 m4 = *(const float4*)&SM[(i0 + r) * PD + j];
                    acc[r] -= m4.x * s0 + m4.y * s1 + m4.z * s2 + m4.w * s3;
                }
            }
#pragma unroll
            for (int il = 1; il < 8; il++)
#pragma unroll
                for (int jl = 0; jl < il; jl++)
                    acc[il] -= SM[(i0 + il) * PD + i0 + jl] * acc[jl];
#pragma unroll
            for (int r = 0; r < 8; r++) sol[i0 + r] = acc[r];
        }
#pragma unroll
        for (int m = 0; m < 64; m++) Uvg[gbase + (size_t)m * 64 + e] = sol[m];
    }
}

// ---------------------------------------------------------------------------
// kC: output, balanced chunk pairs (63-px, px).  (round-5 verbatim)
// ---------------------------------------------------------------------------
__global__ __launch_bounds__(256, 3) void kC(
    const float* __restrict__ qg, const float* __restrict__ WTg,
    const float* __restrict__ UTg, const float* __restrict__ wlast,
    const float* __restrict__ Uvg, float* __restrict__ outg)
{
    const int px = blockIdx.x, bh = blockIdx.y, tid = threadIdx.x;
    __shared__ float X1[64 * 64];
    __shared__ float X2[64 * PD];
    __shared__ float HB[64 * 64];
    const size_t lbase = (size_t)bh * NCC * 64;
    const int t0 = (tid >> 4) * 4, e0 = (tid & 15) * 4;

    for (int pass = 0; pass < 2; ++pass) {
        const int n = pass ? px : 63 - px;
        const size_t qbase = ((size_t)bh * SLEN + (size_t)n * Cc) * Dd;
        const size_t wbase = (size_t)(bh * NCC + n) * Cc * Dd;
        if (pass) __syncthreads();

        float4 qa[4], wt[4];
        float qinv[4];
#pragma unroll
        for (int p = 0; p < 4; p++) {
            const int flat = p * 1024 + tid * 4;
            const int m = flat >> 6, d = flat & 63;
            *(float4*)&X1[m * 64 + d] = *(const float4*)(wlast + lbase + flat);
            *(float4*)&X2[m * PD + d] = *(const float4*)(Uvg + lbase + flat);
            qa[p] = *(const float4*)(qg + qbase + flat);
            float ss = qa[p].x * qa[p].x + qa[p].y * qa[p].y +
                       qa[p].z * qa[p].z + qa[p].w * qa[p].w;
            ss += __shfl_xor(ss, 1); ss += __shfl_xor(ss, 2);
            ss += __shfl_xor(ss, 4); ss += __shfl_xor(ss, 8);
            qinv[p] = 1.0f / (sqrtf(ss) + EPSF);
            wt[p] = *(const float4*)(WTg + wbase + flat);
        }
        __syncthreads();

        float ha[4][4];
#pragma unroll
        for (int r = 0; r < 4; r++)
#pragma unroll
            for (int c2 = 0; c2 < 4; c2++) ha[r][c2] = 0.f;
        for (int m = 0; m < n; m++) {
            const float4 a = *(const float4*)&X1[m * 64 + t0];
            const float4 b = *(const float4*)&X2[m * PD + e0];
            const float av[4] = {a.x, a.y, a.z, a.w};
            const float bv[4] = {b.x, b.y, b.z, b.w};
#pragma unroll
            for (int r = 0; r < 4; r++)
#pragma unroll
                for (int c2 = 0; c2 < 4; c2++) ha[r][c2] += av[r] * bv[c2];
        }
#pragma unroll
        for (int r = 0; r < 4; r++)
            *(float4*)&HB[(t0 + r) * 64 + e0] =
                make_float4(ha[r][0], ha[r][1], ha[r][2], ha[r][3]);
        __syncthreads();

#pragma unroll
        for (int p = 0; p < 4; p++) {
            const int flat = p * 1024 + tid * 4;
            const int d = flat >> 6, t = flat & 63;
            *(float4*)&X1[d * 64 + t] = wt[p];
            const int row = d, d0 = t;
            X2[(d0 + 0) * PD + row] = qa[p].x * qinv[p];
            X2[(d0 + 1) * PD + row] = qa[p].y * qinv[p];
            X2[(d0 + 2) * PD + row] = qa[p].z * qinv[p];
            X2[(d0 + 3) * PD + row] = qa[p].w * qinv[p];
        }
        __syncthreads();

        float kth[4][4], oin[4][4];
#pragma unroll
        for (int r = 0; r < 4; r++)
#pragma unroll
            for (int c2 = 0; c2 < 4; c2++) { kth[r][c2] = 0.f; oin[r][c2] = 0.f; }
#pragma unroll 4
        for (int d = 0; d < 64; d++) {
            const float4 wv = *(const float4*)&X1[d * 64 + t0];
            const float4 qv = *(const float4*)&X2[d * PD + t0];
            const float4 hv = *(const float4*)&HB[d * 64 + e0];
            const float wa[4] = {wv.x, wv.y, wv.z, wv.w};
            const float qa2[4] = {qv.x, qv.y, qv.z, qv.w};
            const float hv4[4] = {hv.x, hv.y, hv.z, hv.w};
#pragma unroll
            for (int r = 0; r < 4; r++)
#pragma unroll
                for (int c2 = 0; c2 < 4; c2++) {
                    kth[r][c2] += wa[r] * hv4[c2];
                    oin[r][c2] += qa2[r] * hv4[c2];
                }
        }

        float* oc = outg + qbase;
        float o4[4][4];
#pragma unroll
        for (int s = 0; s < 4; s++) {
            const float4 u4 = *(const float4*)(UTg + wbase + (size_t)(e0 + s) * 64 + t0);
            const float4 q4 = *(const float4*)&X2[(e0 + s) * PD + t0];
            o4[0][s] = q4.x * (u4.x - kth[0][s]) + oin[0][s];
            o4[1][s] = q4.y * (u4.y - kth[1][s]) + oin[1][s];
            o4[2][s] = q4.z * (u4.z - kth[2][s]) + oin[2][s];
            o4[3][s] = q4.w * (u4.w - kth[3][s]) + oin[3][s];
        }
#pragma unroll
        for (int r = 0; r < 4; r++)
            *(float4*)(oc + (size_t)(t0 + r) * 64 + e0) =
                make_float4(o4[r][0], o4[r][1], o4[r][2], o4[r][3]);
    }
}

extern "C" void kernel_launch(void* const* d_in, const int* in_sizes, int n_in,
                              void* d_out, int out_size, void* d_ws, size_t ws_size,
                              hipStream_t stream) {
    const float* q    = (const float*)d_in[0];
    const float* k    = (const float*)d_in[1];
    const float* v    = (const float*)d_in[2];
    const float* beta = (const float*)d_in[3];
    float* out = (float*)d_out;

    float* WTg   = (float*)d_ws;                              // [BH][NC][64][64]
    float* UTg   = WTg + (size_t)BHn * NCC * Cc * Dd;         // [BH][NC][64][64]
    float* wlast = UTg + (size_t)BHn * NCC * Cc * Dd;         // [BH][NC][64]
    float* ulast = wlast + (size_t)BHn * NCC * 64;            // [BH][NC][64]
    float* Uvg   = ulast + (size_t)BHn * NCC * 64;            // [BH][NC][64]

    kA<<<dim3(NCC, BHn), 256, 0, stream>>>(k, v, beta, WTg, UTg, wlast, ulast);
    kB<<<dim3(BHn), 256, 0, stream>>>(wlast, ulast, Uvg);
    kC<<<dim3(32, BHn), 256, 0, stream>>>(q, WTg, UTg, wlast, Uvg, out);
}